// Round 2
// 490.224 us; speedup vs baseline: 1.0005x; 1.0005x over previous
//
#include <hip/hip_runtime.h>

// HyperConnections fused kernel, MI355X (gfx950). ALL I/O float32.
// Shapes: h (8192, 4, 2048), h_o (8192, 2048), out (8192, 4, 2048).
//
// V2 structure (vs 490us/164us-dispatch baseline):
//  * Algebraic fold: dyn_alpha = rstd*(sum(h*g*A) - mean*sum(g*A)) + sum(b*A),
//    so position-independent constants (sum g*A etc.) move to a one-block prep
//    kernel -> main kernel needs ONE 28-value reduction stage (2 barriers)
//    instead of two dependent stages (4 barriers) + a second pass over hv.
//  * Wave reduction via DPP (row_shr + row_bcast) -> pure VALU, no ds_bpermute
//    chains on the LDS pipe (was 168 DS ops/thread, 6-deep latency chains).
//  * Dense vector mapping: thread owns d in [4t,4t+4) and [1024+4t,+4) so every
//    float4 load/store is a fully-dense 1KB wave access.
//  * Prep kernel also packs {gamma,Bfn} as float2 and A[:,1:5] as float4 in ws
//    (56 scalar const loads/thread -> 12 vector loads).
//  * Nontemporal output stores via native clang vector type (never re-read;
//    keep inputs in L3). HIP float4 is a class type -> rejected by the builtin.

#define NDIM   2048
#define NRATE  4
#define DSCALE 0.01f
#define LEPS   1e-5f

typedef float vfloat4 __attribute__((ext_vector_type(4)));

// ws float layout:
//   [0..9]              c: GA[4]=sum(g*A_k), BA[4]=sum(b*A_k), GB=sum(g*Bfn), BB=sum(b*Bfn)
//   [16   .. 16+4096)   pk2[d] = {gamma[d], Bfn[d]}   (float2, 8B aligned)
//   [4112 .. 4112+8192) pk4[d] = {A[d,1..4]}          (float4, 16B aligned)
#define WS_PK2 16
#define WS_PK4 4112

template <int C>
__device__ __forceinline__ float dppmv(float x) {
    return __builtin_bit_cast(float,
        __builtin_amdgcn_update_dpp(0, __builtin_bit_cast(int, x), C, 0xF, 0xF, true));
}

// Full wave64 sum via DPP; result valid in lane 63.
// row_shr:1,2,4,8 -> lane15/31/47/63 hold row sums; bcast15 then bcast31 combine.
__device__ __forceinline__ float wsum(float x) {
    x += dppmv<0x111>(x);   // row_shr:1
    x += dppmv<0x112>(x);   // row_shr:2
    x += dppmv<0x114>(x);   // row_shr:4
    x += dppmv<0x118>(x);   // row_shr:8
    x += dppmv<0x142>(x);   // row_bcast:15
    x += dppmv<0x143>(x);   // row_bcast:31
    return x;
}

__global__ __launch_bounds__(256) void hc_prep(
    const float* __restrict__ g_, const float* __restrict__ b_,
    const float* __restrict__ Afn, const float* __restrict__ Bfn,
    float* __restrict__ ws)
{
    __shared__ float s_red[4][10];
    const int t = threadIdx.x;
    const int lane = t & 63, wave = t >> 6;
    float acc[10];
    #pragma unroll
    for (int v = 0; v < 10; v++) acc[v] = 0.f;
    #pragma unroll
    for (int i = 0; i < 8; i++) {
        const int d = t * 8 + i;
        const float g  = g_[d];
        const float b  = b_[d];
        const float db = Bfn[d];
        const float a1 = Afn[d*5+1], a2 = Afn[d*5+2], a3 = Afn[d*5+3], a4 = Afn[d*5+4];
        *(float2*)(ws + WS_PK2 + 2*d) = make_float2(g, db);
        *(float4*)(ws + WS_PK4 + 4*d) = make_float4(a1, a2, a3, a4);
        acc[0] = fmaf(g, a1, acc[0]); acc[1] = fmaf(g, a2, acc[1]);
        acc[2] = fmaf(g, a3, acc[2]); acc[3] = fmaf(g, a4, acc[3]);
        acc[4] = fmaf(b, a1, acc[4]); acc[5] = fmaf(b, a2, acc[5]);
        acc[6] = fmaf(b, a3, acc[6]); acc[7] = fmaf(b, a4, acc[7]);
        acc[8] = fmaf(g, db, acc[8]); acc[9] = fmaf(b, db, acc[9]);
    }
    #pragma unroll
    for (int v = 0; v < 10; v++) {
        float w = wsum(acc[v]);
        if (lane == 63) s_red[wave][v] = w;
    }
    __syncthreads();
    if (t < 10) ws[t] = s_red[0][t] + s_red[1][t] + s_red[2][t] + s_red[3][t];
}

__global__ __launch_bounds__(256) void hc_main(
    const float* __restrict__ h,     // (P, 4, 2048)
    const float* __restrict__ h_o,   // (P, 2048)
    const float* __restrict__ sA,    // (4, 5) static_alpha
    const float* __restrict__ sB,    // (4)    static_beta
    const float* __restrict__ ws,
    float* __restrict__ out)         // (P, 4, 2048)
{
    __shared__ float s_red[4][28];
    __shared__ float s_bc[28];

    const int t    = threadIdx.x;
    const int lane = t & 63;
    const int wave = t >> 6;
    const size_t pbase = (size_t)blockIdx.x * (NRATE * NDIM);
    // two dense chunks: d in [4t, 4t+4) and [1024+4t, 1024+4t+4)
    const int dc0 = 4 * t;
    const int dc1 = 1024 + 4 * t;

    // ---- issue all HBM loads first (latency hidden under stage 1 + reduce) ----
    float hv[NRATE][8];
    #pragma unroll
    for (int n = 0; n < NRATE; n++) {
        const float4 r0 = *(const float4*)(h + pbase + n * NDIM + dc0);
        const float4 r1 = *(const float4*)(h + pbase + n * NDIM + dc1);
        hv[n][0] = r0.x; hv[n][1] = r0.y; hv[n][2] = r0.z; hv[n][3] = r0.w;
        hv[n][4] = r1.x; hv[n][5] = r1.y; hv[n][6] = r1.z; hv[n][7] = r1.w;
    }
    const float4 ro0 = *(const float4*)(h_o + (size_t)blockIdx.x * NDIM + dc0);
    const float4 ro1 = *(const float4*)(h_o + (size_t)blockIdx.x * NDIM + dc1);

    // uniform constants (scalar loads, issued early)
    const float GA0 = ws[0], GA1 = ws[1], GA2 = ws[2], GA3 = ws[3];
    const float BA0 = ws[4], BA1 = ws[5], BA2 = ws[6], BA3 = ws[7];
    const float GB  = ws[8], BB  = ws[9];

    // ---- stage 1: all 28 partials in ONE pass over hv ----
    float S[NRATE]  = {0.f, 0.f, 0.f, 0.f};
    float SS[NRATE] = {0.f, 0.f, 0.f, 0.f};
    float Q[NRATE]  = {0.f, 0.f, 0.f, 0.f};
    float Pk[NRATE][4] = {};
    #pragma unroll
    for (int c = 0; c < 2; c++) {
        const int dc = c ? dc1 : dc0;
        #pragma unroll
        for (int i = 0; i < 4; i++) {
            const int d = dc + i;
            const float2 gb = *(const float2*)(ws + WS_PK2 + 2 * d);
            const float4 a  = *(const float4*)(ws + WS_PK4 + 4 * d);
            #pragma unroll
            for (int n = 0; n < NRATE; n++) {
                const float x = hv[n][c * 4 + i];
                S[n] += x;
                SS[n] = fmaf(x, x, SS[n]);
                const float xg = x * gb.x;
                Pk[n][0] = fmaf(xg, a.x, Pk[n][0]);
                Pk[n][1] = fmaf(xg, a.y, Pk[n][1]);
                Pk[n][2] = fmaf(xg, a.z, Pk[n][2]);
                Pk[n][3] = fmaf(xg, a.w, Pk[n][3]);
                Q[n]     = fmaf(xg, gb.y, Q[n]);
            }
        }
    }

    // ---- single 28-value wave reduce (DPP) + cross-wave combine ----
    float red[28];
    #pragma unroll
    for (int n = 0; n < NRATE; n++) {
        red[n]     = S[n];
        red[4 + n] = SS[n];
        red[8 + n] = Q[n];
        #pragma unroll
        for (int k = 0; k < 4; k++) red[12 + n * 4 + k] = Pk[n][k];
    }
    #pragma unroll
    for (int v = 0; v < 28; v++) {
        float w = wsum(red[v]);
        if (lane == 63) s_red[wave][v] = w;
    }
    __syncthreads();
    if (t < 28) s_bc[t] = s_red[0][t] + s_red[1][t] + s_red[2][t] + s_red[3][t];
    __syncthreads();

    // ---- finalize alpha (cols 1..4) and beta per n ----
    float alpha_f[NRATE][4], beta_f[NRATE];
    #pragma unroll
    for (int n = 0; n < NRATE; n++) {
        const float m   = s_bc[n] * (1.0f / NDIM);
        const float var = s_bc[4 + n] * (1.0f / NDIM) - m * m;
        const float rs  = rsqrtf(var + LEPS);
        const float p0 = s_bc[12 + n * 4 + 0], p1 = s_bc[12 + n * 4 + 1];
        const float p2 = s_bc[12 + n * 4 + 2], p3 = s_bc[12 + n * 4 + 3];
        alpha_f[n][0] = fmaf(DSCALE, fmaf(rs, fmaf(-m, GA0, p0), BA0), sA[n * 5 + 1]);
        alpha_f[n][1] = fmaf(DSCALE, fmaf(rs, fmaf(-m, GA1, p1), BA1), sA[n * 5 + 2]);
        alpha_f[n][2] = fmaf(DSCALE, fmaf(rs, fmaf(-m, GA2, p2), BA2), sA[n * 5 + 3]);
        alpha_f[n][3] = fmaf(DSCALE, fmaf(rs, fmaf(-m, GA3, p3), BA3), sA[n * 5 + 4]);
        beta_f[n]     = fmaf(DSCALE, fmaf(rs, fmaf(-m, GB, s_bc[8 + n]), BB), sB[n]);
    }

    // ---- output: out[j,d] = h_o[d]*beta[j] + sum_n alpha[n][j]*h[n,d] ----
    float ho[8];
    ho[0] = ro0.x; ho[1] = ro0.y; ho[2] = ro0.z; ho[3] = ro0.w;
    ho[4] = ro1.x; ho[5] = ro1.y; ho[6] = ro1.z; ho[7] = ro1.w;

    #pragma unroll
    for (int j = 0; j < NRATE; j++) {
        float o[8];
        #pragma unroll
        for (int i = 0; i < 8; i++) {
            float acc = ho[i] * beta_f[j];
            #pragma unroll
            for (int n = 0; n < NRATE; n++) acc = fmaf(alpha_f[n][j], hv[n][i], acc);
            o[i] = acc;
        }
        vfloat4 w0 = { o[0], o[1], o[2], o[3] };
        vfloat4 w1 = { o[4], o[5], o[6], o[7] };
        __builtin_nontemporal_store(w0, (vfloat4*)(out + pbase + j * NDIM + dc0));
        __builtin_nontemporal_store(w1, (vfloat4*)(out + pbase + j * NDIM + dc1));
    }
}

extern "C" void kernel_launch(void* const* d_in, const int* in_sizes, int n_in,
                              void* d_out, int out_size, void* d_ws, size_t ws_size,
                              hipStream_t stream) {
    const float* h   = (const float*)d_in[0];
    const float* h_o = (const float*)d_in[1];
    const float* g   = (const float*)d_in[2];
    const float* b   = (const float*)d_in[3];
    const float* A   = (const float*)d_in[4];
    const float* Bf  = (const float*)d_in[5];
    const float* sA  = (const float*)d_in[6];
    const float* sB  = (const float*)d_in[7];
    float* out = (float*)d_out;
    float* ws  = (float*)d_ws;   // needs ~49 KB; harness workspace is MBs

    const int P = in_sizes[1] / NDIM;   // b*l = 8192
    hc_prep<<<1, 256, 0, stream>>>(g, b, A, Bf, ws);
    hc_main<<<P, 256, 0, stream>>>(h, h_o, sA, sB, ws, out);
}